// Round 1
// 806.494 us; speedup vs baseline: 1.0272x; 1.0272x over previous
//
#include <hip/hip_runtime.h>
#include <cstdint>
#include <cstddef>

// Problem constants (fixed by the reference)
#define TDIM 2048   // tokens (B*S)
#define HDIM 2048   // hidden
#define IDIM 768    // intermediate
#define EXP  32     // experts
#define TOPK 4
#define TKTOT 8192  // TDIM*TOPK
#define MAXMETA 96  // workspace layout slot count (prefix kept identical)
#define CHUNK 256   // rows per expert chunk
#define NMETA 64    // sum_e ceil(cnt_e/256) <= 8192/256 + 32 = 64

typedef __attribute__((ext_vector_type(8))) short short8;
typedef __attribute__((ext_vector_type(4))) float f32x4;

// ---------- workspace layout (prefix identical to previous rounds) ----------
constexpr size_t OFF_XBF = 0;                                      // x bf16 [T][H]
constexpr size_t OFF_ACT = OFF_XBF + (size_t)TDIM * HDIM * 2;      // act bf16 [TKTOT][I]
constexpr size_t OFF_LOG = OFF_ACT + (size_t)TKTOT * IDIM * 2;     // logits f32 [T][E]
constexpr size_t OFF_SEL = OFF_LOG + (size_t)TDIM * EXP * 4;
constexpr size_t OFF_WTS = OFF_SEL + (size_t)TDIM * TOPK * 4;
constexpr size_t OFF_STK = OFF_WTS + (size_t)TDIM * TOPK * 4;
constexpr size_t OFF_SW  = OFF_STK + (size_t)TKTOT * 4;
constexpr size_t OFF_INV = OFF_SW  + (size_t)TKTOT * 4;
constexpr size_t OFF_CNT = OFF_INV + (size_t)TDIM * TOPK * 4;
constexpr size_t OFF_CUR = OFF_CNT + EXP * 4;
constexpr size_t OFF_OFS = OFF_CUR + EXP * 4;
constexpr size_t OFF_MET = OFF_OFS + (EXP + 1) * 4;
constexpr size_t OFF_NB  = OFF_MET + MAXMETA * 2 * 4;
constexpr size_t OFF_TMP = (OFF_NB + 4 + 255) & ~(size_t)255;      // tmp f32 [TKTOT][H]
constexpr size_t TMP_BYTES = (size_t)TKTOT * HDIM * 4;

// ---------- helpers ----------
__device__ __forceinline__ unsigned short f2bf(float f) {  // RNE f32->bf16
  unsigned u = __float_as_uint(f);
  u = (u + 0x7fffu + ((u >> 16) & 1u)) >> 16;
  return (unsigned short)u;
}
__device__ __forceinline__ unsigned pk2(float a, float b) {
  return (unsigned)f2bf(a) | ((unsigned)f2bf(b) << 16);
}
__device__ __forceinline__ void async16(void* lds, const void* g) {
  __builtin_amdgcn_global_load_lds((const __attribute__((address_space(1))) void*)g,
                                   (__attribute__((address_space(3))) void*)lds, 16, 0, 0);
}

// ---------- x f32 -> bf16 ----------
__global__ __launch_bounds__(256) void k_cvt(const float* __restrict__ x,
                                             unsigned short* __restrict__ xb) {
  int i = blockIdx.x * 256 + threadIdx.x;
  const float4* s = (const float4*)x;
  float4 a = s[2 * i], b = s[2 * i + 1];
  uint4 o;
  o.x = pk2(a.x, a.y); o.y = pk2(a.z, a.w);
  o.z = pk2(b.x, b.y); o.w = pk2(b.z, b.w);
  ((uint4*)xb)[i] = o;
}

// ---------- router logits ----------
__global__ __launch_bounds__(256) void k_router(const float* __restrict__ x,
                                                const float* __restrict__ gw,
                                                float* __restrict__ logits) {
  __shared__ float smx[4 * HDIM];
  int tid = threadIdx.x;
  int t0 = blockIdx.x * 4;
  const float4* src = (const float4*)(x + (size_t)t0 * HDIM);
  float4* dst = (float4*)smx;
#pragma unroll
  for (int i = 0; i < 8; i++) dst[i * 256 + tid] = src[i * 256 + tid];
  __syncthreads();
  int e = tid >> 3, sl = tid & 7;
  float acc[4] = {0.f, 0.f, 0.f, 0.f};
  const float* gptr = gw + (size_t)e * HDIM + sl * 256;
#pragma unroll 4
  for (int j = 0; j < 64; j++) {
    float4 g4 = *(const float4*)(gptr + j * 4);
#pragma unroll
    for (int tt = 0; tt < 4; tt++) {
      float4 xa = *(const float4*)&smx[tt * HDIM + sl * 256 + j * 4];
      acc[tt] += g4.x * xa.x + g4.y * xa.y + g4.z * xa.z + g4.w * xa.w;
    }
  }
  __syncthreads();
#pragma unroll
  for (int tt = 0; tt < 4; tt++) smx[(tt * EXP + e) * 8 + sl] = acc[tt];
  __syncthreads();
  if (tid < 128) {
    int tt = tid >> 5, ee = tid & 31;
    float s = 0.f;
#pragma unroll
    for (int q = 0; q < 8; q++) s += smx[(tt * EXP + ee) * 8 + q];
    logits[(size_t)(t0 + tt) * EXP + ee] = s;
  }
}

// ---------- softmax + top-4 + renorm ----------
__global__ __launch_bounds__(256) void k_topk(const float* __restrict__ logits,
                                              int* __restrict__ sel,
                                              float* __restrict__ wts,
                                              int* __restrict__ cnt) {
  int t = blockIdx.x * 256 + threadIdx.x;
  float p[EXP];
  float mx = -1e30f;
#pragma unroll
  for (int e = 0; e < EXP; e++) { p[e] = logits[(size_t)t * EXP + e]; mx = fmaxf(mx, p[e]); }
#pragma unroll
  for (int e = 0; e < EXP; e++) p[e] = __expf(p[e] - mx);
  unsigned used = 0; int si[TOPK]; float sv[TOPK]; float tot = 0.f;
  for (int k = 0; k < TOPK; k++) {
    float bm = -1.f; int bi = 0;
#pragma unroll
    for (int e = 0; e < EXP; e++) {
      bool ok = !((used >> e) & 1) && (p[e] > bm);
      bm = ok ? p[e] : bm;
      bi = ok ? e : bi;
    }
    used |= 1u << bi; si[k] = bi; sv[k] = bm; tot += bm;
  }
  float inv = 1.f / tot;
#pragma unroll
  for (int k = 0; k < TOPK; k++) {
    sel[t * TOPK + k] = si[k];
    wts[t * TOPK + k] = sv[k] * inv;
    atomicAdd(&cnt[si[k]], 1);
  }
}

// ---------- serial scan (CHUNK=256 chunking) ----------
__global__ void k_scan(const int* __restrict__ cnt, int* __restrict__ offs,
                       int* __restrict__ cur, int* __restrict__ meta,
                       int* __restrict__ nb) {
  if (threadIdx.x == 0 && blockIdx.x == 0) {
    int off = 0, n = 0;
    for (int e = 0; e < EXP; e++) {
      offs[e] = off; cur[e] = off;
      int c = cnt[e];
      for (int r = 0; r < c && n < NMETA; r += CHUNK) { meta[n * 2] = e; meta[n * 2 + 1] = r; n++; }
      off += c;
    }
    offs[EXP] = off;
    nb[0] = n;
  }
}

// ---------- scatter ----------
__global__ __launch_bounds__(256) void k_scatter(const int* __restrict__ sel,
                                                 const float* __restrict__ wts,
                                                 int* __restrict__ cur,
                                                 int* __restrict__ stok,
                                                 float* __restrict__ sw,
                                                 int* __restrict__ inv) {
  int t = blockIdx.x * 256 + threadIdx.x;
#pragma unroll
  for (int k = 0; k < TOPK; k++) {
    int e = sel[t * TOPK + k];
    int p = atomicAdd(&cur[e], 1);
    stok[p] = t;
    sw[p] = wts[t * TOPK + k];
    inv[t * TOPK + k] = p;
  }
}

// ---------- GEMM1: f32 weights read directly, M=256 N=64(xG,U) BK=64, dbuf ----------
// 512 threads = 8 waves (4 waveM x 2 waveN). LDS: A 2x32KB + Bg 2x8KB + Bu 2x8KB = 96KB.
__global__ __launch_bounds__(512, 1) void k_gemm1n(
    const float* __restrict__ Wg, const float* __restrict__ Wu,
    const unsigned short* __restrict__ xb,
    const int* __restrict__ stok, const float* __restrict__ sw,
    const int* __restrict__ cnt, const int* __restrict__ offs,
    const int* __restrict__ meta, const int* __restrict__ nb,
    unsigned short* __restrict__ act) {
  // 8x8 transpose swizzle on 64 blocks: chunk-mates (adjacent logical bids) land
  // on raw ids differing by 8 -> same XCD -> second chunk's weight stream L2-hits.
  int bid = (blockIdx.x & 7) * 8 + (blockIdx.x >> 3);
  if (bid >= nb[0]) return;
  int e = meta[bid * 2], r0 = meta[bid * 2 + 1];
  int pos0 = offs[e] + r0;
  int rows = min(CHUNK, cnt[e] - r0);
  int n0 = blockIdx.y * 64;

  __shared__ unsigned short smA[2][CHUNK * 64];   // 2 x 32 KB
  __shared__ unsigned short smBg[2][64 * 64];     // 2 x 8 KB
  __shared__ unsigned short smBu[2][64 * 64];     // 2 x 8 KB
  __shared__ int smTok[CHUNK];
  __shared__ float smW[CHUNK];

  int tid = threadIdx.x;
  if (tid < CHUNK) {
    int rr = (tid < rows) ? tid : 0;
    smTok[tid] = stok[pos0 + rr];
    smW[tid] = (tid < rows) ? sw[pos0 + tid] : 0.f;
  }
  __syncthreads();

  int lane = tid & 63, w = tid >> 6;
  int waveM = w >> 1, waveN = w & 1;

  // A staging: 4 rounds x 64 rows; pre-swizzled global source, linear LDS dest
  const unsigned short* aC[4];
#pragma unroll
  for (int p = 0; p < 4; p++) {
    int r = p * 64 + w * 8 + (lane >> 3);
    aC[p] = xb + (size_t)smTok[r] * HDIM + (((lane & 7) ^ (r & 7)) << 3);
  }
  // B staging: thread owns column n=bn, k-rows kh*8..+8 (f32, coalesced 256B/wave)
  size_t wb = (size_t)e * HDIM * IDIM;
  int bn = tid & 63, kh = tid >> 6;   // kh == wave id, 0..7
  const float* pG = Wg + wb + (size_t)(kh * 8) * IDIM + n0 + bn;
  const float* pU = Wu + wb + (size_t)(kh * 8) * IDIM + n0 + bn;
  int bOff = bn * 64 + ((kh ^ (bn & 7)) << 3);

  f32x4 accG[4][2], accU[4][2];
#pragma unroll
  for (int a = 0; a < 4; a++)
#pragma unroll
    for (int b = 0; b < 2; b++) { accG[a][b] = {0.f,0.f,0.f,0.f}; accU[a][b] = {0.f,0.f,0.f,0.f}; }

  int lm = lane & 15, lq = lane >> 4;
  float vg[8], vu[8];

  // prologue: stage kt=0 into buf0
#pragma unroll
  for (int p = 0; p < 4; p++) async16(&smA[0][(p * 64 + w * 8) * 64], aC[p]);
#pragma unroll
  for (int j = 0; j < 8; j++) { vg[j] = pG[(size_t)j * IDIM]; vu[j] = pU[(size_t)j * IDIM]; }
  {
    short8 og, ou;
#pragma unroll
    for (int z = 0; z < 8; z++) { og[z] = (short)f2bf(vg[z]); ou[z] = (short)f2bf(vu[z]); }
    *(short8*)&smBg[0][bOff] = og;
    *(short8*)&smBu[0][bOff] = ou;
  }
  __syncthreads();

  const int NK = HDIM / 64;  // 32
  for (int kt = 0; kt < NK; kt++) {
    int c = kt & 1;
    if (kt + 1 < NK) {
      // prefetch kt+1 into the other buffer: loads fly under the MFMA phase
#pragma unroll
      for (int p = 0; p < 4; p++) { aC[p] += 64; async16(&smA[c ^ 1][(p * 64 + w * 8) * 64], aC[p]); }
      pG += (size_t)64 * IDIM; pU += (size_t)64 * IDIM;
#pragma unroll
      for (int j = 0; j < 8; j++) { vg[j] = pG[(size_t)j * IDIM]; vu[j] = pU[(size_t)j * IDIM]; }
    }
#pragma unroll
    for (int s = 0; s < 2; s++) {
      int kq = s * 4 + lq;
      short8 af[4], bg[2], bu[2];
#pragma unroll
      for (int mt = 0; mt < 4; mt++) {
        int m = waveM * 64 + mt * 16 + lm;
        af[mt] = *(const short8*)&smA[c][m * 64 + ((kq ^ (m & 7)) << 3)];
      }
#pragma unroll
      for (int nt = 0; nt < 2; nt++) {
        int n = waveN * 32 + nt * 16 + lm;
        int off = n * 64 + ((kq ^ (n & 7)) << 3);
        bg[nt] = *(const short8*)&smBg[c][off];
        bu[nt] = *(const short8*)&smBu[c][off];
      }
#pragma unroll
      for (int mt = 0; mt < 4; mt++)
#pragma unroll
        for (int nt = 0; nt < 2; nt++) {
          accG[mt][nt] = __builtin_amdgcn_mfma_f32_16x16x32_bf16(af[mt], bg[nt], accG[mt][nt], 0, 0, 0);
          accU[mt][nt] = __builtin_amdgcn_mfma_f32_16x16x32_bf16(af[mt], bu[nt], accU[mt][nt], 0, 0, 0);
        }
    }
    if (kt + 1 < NK) {
      short8 og, ou;
#pragma unroll
      for (int z = 0; z < 8; z++) { og[z] = (short)f2bf(vg[z]); ou[z] = (short)f2bf(vu[z]); }
      *(short8*)&smBg[c ^ 1][bOff] = og;
      *(short8*)&smBu[c ^ 1][bOff] = ou;
    }
    __syncthreads();
  }

#pragma unroll
  for (int mt = 0; mt < 4; mt++)
#pragma unroll
    for (int nt = 0; nt < 2; nt++) {
      int n = n0 + waveN * 32 + nt * 16 + lm;
#pragma unroll
      for (int i = 0; i < 4; i++) {
        int r = waveM * 64 + mt * 16 + lq * 4 + i;
        if (r < rows) {
          float g = accG[mt][nt][i], u = accU[mt][nt][i];
          float sg = g / (1.f + __expf(-g));
          act[(size_t)(pos0 + r) * IDIM + n] = f2bf(sg * u * smW[r]);
        }
      }
    }
}

// ---------- GEMM2: f32 Wd read directly, M=256 N=128 BK=64, dbuf ----------
// 512 threads = 8 waves. LDS: A 2x32KB + B 2x16KB = 96KB.
__global__ __launch_bounds__(512, 1) void k_gemm2n(
    const float* __restrict__ Wd, const unsigned short* __restrict__ act,
    const int* __restrict__ stok, const int* __restrict__ cnt,
    const int* __restrict__ offs, const int* __restrict__ meta,
    const int* __restrict__ nb, float* __restrict__ dst, int mode) {
  int bid = (blockIdx.x & 7) * 8 + (blockIdx.x >> 3);
  if (bid >= nb[0]) return;
  int e = meta[bid * 2], r0 = meta[bid * 2 + 1];
  int pos0 = offs[e] + r0;
  int rows = min(CHUNK, cnt[e] - r0);
  int n0 = blockIdx.y * 128;

  __shared__ unsigned short smA[2][CHUNK * 64];  // 2 x 32 KB
  __shared__ unsigned short smB[2][128 * 64];    // 2 x 16 KB
  __shared__ int smTok[CHUNK];

  int tid = threadIdx.x;
  if (tid < CHUNK) {
    int rr = (tid < rows) ? tid : 0;
    smTok[tid] = stok[pos0 + rr];
  }
  __syncthreads();

  int lane = tid & 63, w = tid >> 6;
  int waveM = w >> 1, waveN = w & 1;

  const unsigned short* aC[4];
#pragma unroll
  for (int p = 0; p < 4; p++) {
    int r = p * 64 + w * 8 + (lane >> 3);
    int pp = pos0 + r; if (pp > TKTOT - 1) pp = TKTOT - 1;
    aC[p] = act + (size_t)pp * IDIM + (((lane & 7) ^ (r & 7)) << 3);
  }
  size_t wb = (size_t)e * IDIM * HDIM;  // Wd is [E][I][H]
  int bn = tid & 127, kh = tid >> 7;    // kh 0..3, 16 k-rows each
  const float* pD = Wd + wb + (size_t)(kh * 16) * HDIM + n0 + bn;

  f32x4 acc[4][4];
#pragma unroll
  for (int a = 0; a < 4; a++)
#pragma unroll
    for (int b = 0; b < 4; b++) acc[a][b] = {0.f, 0.f, 0.f, 0.f};

  int lm = lane & 15, lq = lane >> 4;
  float v[16];

  // prologue
#pragma unroll
  for (int p = 0; p < 4; p++) async16(&smA[0][(p * 64 + w * 8) * 64], aC[p]);
#pragma unroll
  for (int j = 0; j < 16; j++) v[j] = pD[(size_t)j * HDIM];
#pragma unroll
  for (int jj = 0; jj < 2; jj++) {
    short8 o;
#pragma unroll
    for (int z = 0; z < 8; z++) o[z] = (short)f2bf(v[jj * 8 + z]);
    *(short8*)&smB[0][bn * 64 + (((kh * 2 + jj) ^ (bn & 7)) << 3)] = o;
  }
  __syncthreads();

  const int NK = IDIM / 64;  // 12
  for (int kt = 0; kt < NK; kt++) {
    int c = kt & 1;
    if (kt + 1 < NK) {
#pragma unroll
      for (int p = 0; p < 4; p++) { aC[p] += 64; async16(&smA[c ^ 1][(p * 64 + w * 8) * 64], aC[p]); }
      pD += (size_t)64 * HDIM;
#pragma unroll
      for (int j = 0; j < 16; j++) v[j] = pD[(size_t)j * HDIM];
    }
#pragma unroll
    for (int s = 0; s < 2; s++) {
      int kq = s * 4 + lq;
      short8 af[4], bf[4];
#pragma unroll
      for (int mt = 0; mt < 4; mt++) {
        int m = waveM * 64 + mt * 16 + lm;
        af[mt] = *(const short8*)&smA[c][m * 64 + ((kq ^ (m & 7)) << 3)];
      }
#pragma unroll
      for (int nt = 0; nt < 4; nt++) {
        int n = waveN * 64 + nt * 16 + lm;
        bf[nt] = *(const short8*)&smB[c][n * 64 + ((kq ^ (n & 7)) << 3)];
      }
#pragma unroll
      for (int mt = 0; mt < 4; mt++)
#pragma unroll
        for (int nt = 0; nt < 4; nt++)
          acc[mt][nt] = __builtin_amdgcn_mfma_f32_16x16x32_bf16(af[mt], bf[nt], acc[mt][nt], 0, 0, 0);
    }
    if (kt + 1 < NK) {
#pragma unroll
      for (int jj = 0; jj < 2; jj++) {
        short8 o;
#pragma unroll
        for (int z = 0; z < 8; z++) o[z] = (short)f2bf(v[jj * 8 + z]);
        *(short8*)&smB[c ^ 1][bn * 64 + (((kh * 2 + jj) ^ (bn & 7)) << 3)] = o;
      }
    }
    __syncthreads();
  }

#pragma unroll
  for (int mt = 0; mt < 4; mt++)
#pragma unroll
    for (int nt = 0; nt < 4; nt++) {
      int n = n0 + waveN * 64 + nt * 16 + lm;
#pragma unroll
      for (int i = 0; i < 4; i++) {
        int r = waveM * 64 + mt * 16 + lq * 4 + i;
        if (r < rows) {
          float val = acc[mt][nt][i];
          if (mode == 0) {
            dst[(size_t)(pos0 + r) * HDIM + n] = val;
          } else {
            __hip_atomic_fetch_add(&dst[(size_t)smTok[r] * HDIM + n], val,
                                   __ATOMIC_RELAXED, __HIP_MEMORY_SCOPE_AGENT);
          }
        }
      }
    }
}

// ---------- gather-reduce ----------
__global__ __launch_bounds__(256) void k_reduce(const float* __restrict__ tmp,
                                                const int* __restrict__ inv,
                                                float* __restrict__ out) {
  int u = blockIdx.x * 256 + threadIdx.x;
  int t = u >> 9, c = u & 511;
  int i0 = inv[t * 4 + 0], i1 = inv[t * 4 + 1], i2 = inv[t * 4 + 2], i3 = inv[t * 4 + 3];
  float4 a = *(const float4*)(tmp + (size_t)i0 * HDIM + c * 4);
  float4 b = *(const float4*)(tmp + (size_t)i1 * HDIM + c * 4);
  float4 d = *(const float4*)(tmp + (size_t)i2 * HDIM + c * 4);
  float4 e = *(const float4*)(tmp + (size_t)i3 * HDIM + c * 4);
  float4 s;
  s.x = a.x + b.x + d.x + e.x;
  s.y = a.y + b.y + d.y + e.y;
  s.z = a.z + b.z + d.z + e.z;
  s.w = a.w + b.w + d.w + e.w;
  *(float4*)(out + (size_t)t * HDIM + c * 4) = s;
}

extern "C" void kernel_launch(void* const* d_in, const int* in_sizes, int n_in,
                              void* d_out, int out_size, void* d_ws, size_t ws_size,
                              hipStream_t stream) {
  const float* x  = (const float*)d_in[0];
  const float* gw = (const float*)d_in[1];
  const float* Wg = (const float*)d_in[2];
  const float* Wu = (const float*)d_in[3];
  const float* Wd = (const float*)d_in[4];
  float* out = (float*)d_out;

  char* ws = (char*)d_ws;
  unsigned short* xb  = (unsigned short*)(ws + OFF_XBF);
  unsigned short* act = (unsigned short*)(ws + OFF_ACT);
  float* logits = (float*)(ws + OFF_LOG);
  int*   sel    = (int*)(ws + OFF_SEL);
  float* wts    = (float*)(ws + OFF_WTS);
  int*   stok   = (int*)(ws + OFF_STK);
  float* sw     = (float*)(ws + OFF_SW);
  int*   inv    = (int*)(ws + OFF_INV);
  int*   cnt    = (int*)(ws + OFF_CNT);
  int*   cur    = (int*)(ws + OFF_CUR);
  int*   offs   = (int*)(ws + OFF_OFS);
  int*   meta   = (int*)(ws + OFF_MET);
  int*   nb     = (int*)(ws + OFF_NB);
  float* tmp    = (float*)(ws + OFF_TMP);

  bool useTmp = ws_size >= OFF_TMP + TMP_BYTES;

  hipMemsetAsync(cnt, 0, EXP * 4, stream);
  k_cvt<<<(TDIM * HDIM / 8) / 256, 256, 0, stream>>>(x, xb);
  k_router<<<TDIM / 4, 256, 0, stream>>>(x, gw, logits);
  k_topk<<<TDIM / 256, 256, 0, stream>>>(logits, sel, wts, cnt);
  k_scan<<<1, 64, 0, stream>>>(cnt, offs, cur, meta, nb);
  k_scatter<<<TDIM / 256, 256, 0, stream>>>(sel, wts, cur, stok, sw, inv);

  k_gemm1n<<<dim3(NMETA, IDIM / 64), 512, 0, stream>>>(Wg, Wu, xb, stok, sw, cnt, offs, meta, nb, act);
  if (useTmp) {
    k_gemm2n<<<dim3(NMETA, HDIM / 128), 512, 0, stream>>>(Wd, act, stok, cnt, offs, meta, nb, tmp, 0);
    k_reduce<<<(TDIM * 512) / 256, 256, 0, stream>>>(tmp, inv, out);
  } else {
    hipMemsetAsync(out, 0, (size_t)TDIM * HDIM * 4, stream);
    k_gemm2n<<<dim3(NMETA, HDIM / 128), 512, 0, stream>>>(Wd, act, stok, cnt, offs, meta, nb, out, 1);
  }
}